// Round 1
// baseline (122.451 us; speedup 1.0000x reference)
//
#include <hip/hip_runtime.h>

#define T_STEPS 128
#define DIM 1024
#define ODE_UNFOLDS 6
#define EPS 1e-8f
#define L2E 1.44269504088896340736f

__device__ __forceinline__ float fexp2(float x) { return __builtin_amdgcn_exp2f(x); }
__device__ __forceinline__ float frcp(float x)  { return __builtin_amdgcn_rcpf(x); }

__device__ __forceinline__ float softplus_init(float x) {
  // init-only (once per thread); x in (0,1] here so no overflow concerns
  return log2f(1.0f + exp2f(x * L2E)) * (1.0f / L2E);
}

// swap adjacent lane pairs (0<->1, 2<->3, ...): v_mov_b32_dpp quad_perm:[1,0,3,2]
// full-rate VALU, no LDS/lgkm latency on the recurrence critical path
__device__ __forceinline__ float swap_adj(float x) {
  int y = __builtin_amdgcn_mov_dpp(__float_as_int(x), 0xB1, 0xF, 0xF, true);
  return __int_as_float(y);
}

__global__ __launch_bounds__(256) void memcell_kernel(
    const float* __restrict__ inputs,      // (B,T,DIM)
    const float* __restrict__ gleak,       // (U)
    const float* __restrict__ vleak,       // (U)
    const float* __restrict__ cm,          // (U)
    const float* __restrict__ w,           // (U,2)
    const float* __restrict__ sigma,       // (U,2)
    const float* __restrict__ mu,          // (U,2)
    const float* __restrict__ erev,        // (U,2)
    const float* __restrict__ sens_w,      // (U)
    const float* __restrict__ sens_sigma,  // (U)
    const float* __restrict__ sens_mu,     // (U)
    const float* __restrict__ sens_erev,   // (U)
    const float* __restrict__ input_w,     // (DIM)
    const float* __restrict__ input_b,     // (DIM)
    const float* __restrict__ output_w,    // (DIM)
    const float* __restrict__ output_b,    // (DIM)
    float* __restrict__ out)               // (B,DIM)
{
  const int tid  = blockIdx.x * blockDim.x + threadIdx.x;  // [0, B*U)
  const int p    = tid >> 1;          // chain index: b*DIM + col
  const int half = tid & 1;           // 0: unit=col, 1: unit=col+DIM
  const int b    = p >> 10;           // DIM == 1024
  const int col  = p & (DIM - 1);
  const int u    = col + (half << 10);

  // ---- per-thread constants (loaded/derived once) ----
  const float spw0  = softplus_init(w[2*u]);
  const float spw1  = softplus_init(w[2*u+1]);
  const float e0    = erev[2*u];
  const float e1    = erev[2*u+1];
  const float spw0e = spw0 * e0;
  const float spw1e = spw1 * e1;
  const float sg0   = sigma[2*u],  sg1 = sigma[2*u+1];
  const float mu0   = mu[2*u],     mu1 = mu[2*u+1];
  // sigmoid((v-mu)*sg) = 1/(1 + exp2(fma(v, -sg*L2E, mu*sg*L2E)))
  const float negA0 = -sg0 * L2E,  B0c = mu0 * sg0 * L2E;
  const float negA1 = -sg1 * L2E,  B1c = mu1 * sg1 * L2E;
  const float gl    = softplus_init(gleak[u]);
  const float glv   = gl * vleak[u];
  const float cmt   = softplus_init(cm[u]) * (float)ODE_UNFOLDS;
  const float dbase = cmt + gl + EPS;
  const float spsw  = softplus_init(sens_w[u]);
  const float ssg   = sens_sigma[u];
  const float smu   = sens_mu[u];
  const float negAs = -ssg * L2E,  Bsc = smu * ssg * L2E;
  const float serev = sens_erev[u];
  const float iw    = input_w[col];
  const float ib    = input_b[col];

  const float* xp = inputs + ((size_t)b * T_STEPS) * DIM + col;

  // 4-deep x prefetch pipeline (hides HBM latency at 1 wave/SIMD)
  float xs0 = xp[0 * DIM];
  float xs1 = xp[1 * DIM];
  float xs2 = xp[2 * DIM];
  float xs3 = xp[3 * DIM];

  float v = 0.0f;

  for (int tb = 0; tb < T_STEPS; tb += 4) {
    const float c0 = xs0, c1 = xs1, c2 = xs2, c3 = xs3;
    if (tb + 4 < T_STEPS) {
      const float* nx = xp + (size_t)(tb + 4) * DIM;
      xs0 = nx[0 * DIM];
      xs1 = nx[1 * DIM];
      xs2 = nx[2 * DIM];
      xs3 = nx[3 * DIM];
    }
    #pragma unroll
    for (int j = 0; j < 4; ++j) {
      const float xr = (j == 0) ? c0 : (j == 1) ? c1 : (j == 2) ? c2 : c3;
      const float x  = fmaf(xr, iw, ib);
      // sensory synapse (once per step)
      const float ts = fexp2(fmaf(x, negAs, Bsc));
      const float s  = spsw * frcp(1.0f + ts);
      const float ns = fmaf(s, serev, glv);   // glv + num_s
      const float ds = dbase + s;             // cmt + gl + eps + den_s
      #pragma unroll
      for (int k = 0; k < ODE_UNFOLDS; ++k) {
        const float vp = swap_adj(v);         // partner's OLD v (pre-update)
        const float t0 = fexp2(fmaf(v,  negA0, B0c));
        const float t1 = fexp2(fmaf(vp, negA1, B1c));
        const float a0 = 1.0f + t0;
        const float a1 = 1.0f + t1;
        // wa0 = spw0/a0, wa1 = spw1/a1. Multiply num & den through by
        // D = a0*a1 -> single rcp per unfold:
        //   v = (numerN*D + spw0e*a1 + spw1e*a0) / (ds*D + spw0*a1 + spw1*a0)
        const float D      = a0 * a1;
        const float S      = fmaf(spw0,  a1, spw1  * a0);
        const float E      = fmaf(spw0e, a1, spw1e * a0);
        const float numerN = fmaf(cmt, v, ns);
        const float nume   = fmaf(numerN, D, E);
        const float deno   = fmaf(ds, D, S);
        v = nume * frcp(deno);
      }
    }
  }

  if (half == 0) {
    out[(size_t)b * DIM + col] = fmaf(v, output_w[col], output_b[col]);
  }
}

extern "C" void kernel_launch(void* const* d_in, const int* in_sizes, int n_in,
                              void* d_out, int out_size, void* d_ws, size_t ws_size,
                              hipStream_t stream) {
  const float* inputs      = (const float*)d_in[0];
  const float* gleak       = (const float*)d_in[1];
  const float* vleak       = (const float*)d_in[2];
  const float* cm          = (const float*)d_in[3];
  const float* w           = (const float*)d_in[4];
  const float* sigma       = (const float*)d_in[5];
  const float* mu          = (const float*)d_in[6];
  const float* erev        = (const float*)d_in[7];
  const float* sens_w      = (const float*)d_in[8];
  const float* sens_sigma  = (const float*)d_in[9];
  const float* sens_mu     = (const float*)d_in[10];
  const float* sens_erev   = (const float*)d_in[11];
  const float* input_w     = (const float*)d_in[12];
  const float* input_b     = (const float*)d_in[13];
  const float* output_w    = (const float*)d_in[14];
  const float* output_b    = (const float*)d_in[15];

  const int B = in_sizes[0] / (T_STEPS * DIM);   // 32
  const int U = 2 * DIM;
  const int total_threads = B * U;               // 65536
  dim3 block(256);
  dim3 grid(total_threads / 256);                // 256 blocks -> 1 block/CU

  memcell_kernel<<<grid, block, 0, stream>>>(
      inputs, gleak, vleak, cm, w, sigma, mu, erev,
      sens_w, sens_sigma, sens_mu, sens_erev,
      input_w, input_b, output_w, output_b, (float*)d_out);
}